// Round 1
// baseline (422.664 us; speedup 1.0000x reference)
//
#include <hip/hip_runtime.h>
#include <math.h>

#define NB 32
#define NA 5
#define NC 80
#define NH 76
#define NW 76
#define MAXT 50
#define HW (NH*NW)      // 5776
#define CHN (5+NC)      // 85
#define THRESH 0.6f
#define OBJ_SCALE 5.0f

// Anchor (w,h) pairs
__constant__ float c_anchors[10] = {
    1.3221f, 1.73145f, 3.19275f, 4.00944f, 5.05587f,
    8.09892f, 9.47112f, 4.84053f, 11.2364f, 10.0071f};

// Workspace record layout per target (two 8-float regions):
//  recA[(b*MAXT+t)*8] = {x1, x2, y1, y2, gw, gh, area, key(int bits)}
//  recB[(b*MAXT+t)*8] = {tx, ty, tw, th, tconf, tcls(int bits), 0, 0}
// Invalid targets: recA = {+INF,-INF,+INF,-INF,0,0,0,-1} -> IoU contribution
// exactly 0 and key never matches, so phase 2 is branch-free.

__global__ void prep_kernel(const float* __restrict__ out,
                            const float* __restrict__ tgt,
                            float* __restrict__ recA,
                            float* __restrict__ recB,
                            float* __restrict__ loss_out) {
  int b = blockIdx.x;
  int t = threadIdx.x;
  if (b == 0 && t == 0) *loss_out = 0.0f;

  float g0 = 0.f, g1 = 0.f, g2 = 0.f, g3 = 0.f, g4 = 0.f;
  bool flag = true;
  if (t < MAXT) {
    const float* p = tgt + ((size_t)b * MAXT + t) * 5;
    g0 = p[0]; g1 = p[1]; g2 = p[2]; g3 = p[3]; g4 = p[4];
    flag = (g1 != 0.0f);
  }
  unsigned long long mask = __ballot(flag);
  if (t >= MAXT) return;
  // cumulative-product validity: valid iff this and all earlier flags set
  bool valid = flag && (((~mask) & ((1ULL << t) - 1ULL)) == 0ULL);

  float* rA = recA + ((size_t)b * MAXT + t) * 8;
  float* rB = recB + ((size_t)b * MAXT + t) * 8;

  if (!valid) {
    rA[0] =  INFINITY; rA[1] = -INFINITY;
    rA[2] =  INFINITY; rA[3] = -INFINITY;
    rA[4] = 0.f; rA[5] = 0.f; rA[6] = 0.f;
    rA[7] = __int_as_float(-1);
    rB[0] = rB[1] = rB[2] = rB[3] = rB[4] = 0.f;
    rB[5] = __int_as_float(0);
    rB[6] = rB[7] = 0.f;
    return;
  }

  float gx = g1 * NW, gy = g2 * NH, gw = g3 * NW, gh = g4 * NH;

  // anchor argmax (shape-only IoU); first-max wins like jnp.argmax
  int best = 0; float bestiou = -1.0f;
  for (int a = 0; a < NA; a++) {
    float aw = c_anchors[2*a], ah = c_anchors[2*a+1];
    float inter = fminf(gw, aw) * fminf(gh, ah);
    float uni = gw * gh + aw * ah - inter;
    float iou = inter / uni;
    if (iou > bestiou) { bestiou = iou; best = a; }
  }
  float aw = c_anchors[2*best], ah = c_anchors[2*best+1];

  int gi = (int)gx, gj = (int)gy;
  int cgi = min(max(gi, 0), NW - 1);
  int cgj = min(max(gj, 0), NH - 1);

  // matched pred box at (b, best, gj, gi)
  const float* ob = out + (((size_t)b * NA + best) * CHN) * HW + (size_t)cgj * NW + cgi;
  float ox = ob[0*HW], oy = ob[1*HW], ow = ob[2*HW], oh = ob[3*HW];
  float px = 1.0f / (1.0f + expf(-ox)) + (float)cgi;
  float py = 1.0f / (1.0f + expf(-oy)) + (float)cgj;
  float pw = expf(ow) * aw;
  float ph = expf(oh) * ah;

  // t_iou = iou(gt_box, matched_pred)
  float mx = fminf(gx - 0.5f*gw, px - 0.5f*pw);
  float Mx = fmaxf(gx + 0.5f*gw, px + 0.5f*pw);
  float my = fminf(gy - 0.5f*gh, py - 0.5f*ph);
  float My = fmaxf(gy + 0.5f*gh, py + 0.5f*ph);
  float cw = gw + pw - (Mx - mx);
  float chh = gh + ph - (My - my);
  float inter = (cw <= 0.f || chh <= 0.f) ? 0.f : cw * chh;
  float uni = gw * gh + pw * ph - inter;
  float tconf = inter / uni;

  rA[0] = gx - 0.5f*gw; rA[1] = gx + 0.5f*gw;
  rA[2] = gy - 0.5f*gh; rA[3] = gy + 0.5f*gh;
  rA[4] = gw; rA[5] = gh; rA[6] = gw * gh;
  bool inb = (gi >= 0 && gi < NW && gj >= 0 && gj < NH);
  int key = inb ? ((best << 20) | (gj << 10) | gi) : -1;
  rA[7] = __int_as_float(key);

  rB[0] = gx - (float)gi;
  rB[1] = gy - (float)gj;
  rB[2] = logf(gw / aw);
  rB[3] = logf(gh / ah);
  rB[4] = tconf;
  rB[5] = __int_as_float((int)g0);
  rB[6] = 0.f; rB[7] = 0.f;
}

__global__ __launch_bounds__(256) void region_loss_kernel(
    const float* __restrict__ out,
    const float* __restrict__ recA,
    const float* __restrict__ recB,
    float* __restrict__ loss_out) {
  __shared__ float4 sA[MAXT * 2];   // {x1,x2,y1,y2},{gw,gh,area,key}
  __shared__ float  sB[MAXT * 8];   // tx,ty,tw,th,tconf,tcls,_,_
  int b = blockIdx.z, a = blockIdx.y;

  const float4* gA = (const float4*)(recA) + (size_t)b * MAXT * 2;
  for (int idx = threadIdx.x; idx < MAXT * 2; idx += 256) sA[idx] = gA[idx];
  const float* gB = recB + (size_t)b * MAXT * 8;
  for (int idx = threadIdx.x; idx < MAXT * 8; idx += 256) sB[idx] = gB[idx];
  __syncthreads();

  int hw = blockIdx.x * 256 + threadIdx.x;
  float local = 0.0f;
  if (hw < HW) {
    int j = hw / NW;
    int i = hw - j * NW;
    const float* ob = out + (((size_t)b * NA + a) * CHN) * HW + hw;
    float o0 = ob[0*HW], o1 = ob[1*HW], o2 = ob[2*HW], o3 = ob[3*HW], o4 = ob[4*HW];

    float x    = 1.0f / (1.0f + __expf(-o0));
    float y    = 1.0f / (1.0f + __expf(-o1));
    float conf = 1.0f / (1.0f + __expf(-o4));
    float aw = c_anchors[2*a], ah = c_anchors[2*a+1];
    float pw = __expf(o2) * aw;
    float ph = __expf(o3) * ah;
    float px = x + (float)i, py = y + (float)j;
    float px1 = px - 0.5f*pw, px2 = px + 0.5f*pw;
    float py1 = py - 0.5f*ph, py2 = py + 0.5f*ph;
    float parea = pw * ph;
    int mykey = (a << 20) | (j << 10) | i;

    bool over = false;
    int mt = -1;
    for (int t = 0; t < MAXT; t++) {
      float4 p1 = sA[2*t];
      float4 p2 = sA[2*t + 1];
      float mx = fminf(px1, p1.x);
      float Mx = fmaxf(px2, p1.y);
      float my = fminf(py1, p1.z);
      float My = fmaxf(py2, p1.w);
      float cw  = pw + p2.x - (Mx - mx);
      float chh = ph + p2.y - (My - my);
      float inter = (cw <= 0.f || chh <= 0.f) ? 0.f : cw * chh;
      float uni = parea + p2.z - inter;
      over = over || (inter > THRESH * uni);       // iou > THRESH, division-free
      if (__float_as_int(p2.w) == mykey) mt = t;   // last match wins
    }

    if (mt >= 0) {
      const float* r = sB + mt * 8;
      float dx = x - r[0], dy = y - r[1];
      float dw = o2 - r[2], dh = o3 - r[3];
      float dc = conf - r[4];
      local = 0.5f * (dx*dx + dy*dy + dw*dw + dh*dh)
            + 0.5f * OBJ_SCALE * dc * dc;
      // class cross-entropy via one-pass online log-sum-exp
      int tc = __float_as_int(r[5]);
      float m = -1e30f, s = 0.0f, lt = 0.0f;
      for (int c = 0; c < NC; c++) {
        float l = ob[(5 + c) * HW];
        if (c == tc) lt = l;
        if (l > m) { s = s * __expf(m - l) + 1.0f; m = l; }
        else       { s += __expf(l - m); }
      }
      local += (m + logf(s)) - lt;   // CLASS_SCALE = 1
    } else {
      local += over ? 0.0f : 0.5f * conf * conf;   // NOOBJ_SCALE = 1
    }
  }

  // wave reduce (64 lanes) then block reduce
  for (int off = 32; off > 0; off >>= 1) local += __shfl_down(local, off, 64);
  __shared__ float wsum[4];
  int wid = threadIdx.x >> 6;
  int lane = threadIdx.x & 63;
  if (lane == 0) wsum[wid] = local;
  __syncthreads();
  if (threadIdx.x == 0) {
    atomicAdd(loss_out, wsum[0] + wsum[1] + wsum[2] + wsum[3]);
  }
}

extern "C" void kernel_launch(void* const* d_in, const int* in_sizes, int n_in,
                              void* d_out, int out_size, void* d_ws, size_t ws_size,
                              hipStream_t stream) {
  const float* out = (const float*)d_in[0];
  const float* tgt = (const float*)d_in[1];
  float* recA = (float*)d_ws;                       // NB*MAXT*8 floats
  float* recB = recA + (size_t)NB * MAXT * 8;       // NB*MAXT*8 floats
  float* loss = (float*)d_out;

  prep_kernel<<<NB, 64, 0, stream>>>(out, tgt, recA, recB, loss);

  dim3 grid((HW + 255) / 256, NA, NB);
  region_loss_kernel<<<grid, 256, 0, stream>>>(out, recA, recB, loss);
}